// Round 5
// baseline (1654.773 us; speedup 1.0000x reference)
//
#include <hip/hip_runtime.h>
#include <float.h>

#define NPIX 16384    // B*H*W pixels
#define NE   8192     // codebook entries
#define KD   256      // channels
#define HW   1024
#define BCHW 262144
#define DELTA 4e-5f
#define NT   8        // N-tiles (128 codes each) per wg -> wg spans 1024 codes
#define CAND_CAP 524288u

typedef __attribute__((ext_vector_type(8))) short short8;
typedef __attribute__((ext_vector_type(4))) short short4v;
typedef __attribute__((ext_vector_type(4))) float f32x4;
typedef unsigned long long u64;
typedef unsigned int u32;

__device__ __forceinline__ u32 fkey(float f) {
    u32 u = __float_as_uint(f);
    return u ^ ((u >> 31) ? 0xFFFFFFFFu : 0x80000000u);
}
__device__ __forceinline__ float unfkey(u32 k) {
    return __uint_as_float((k >> 31) ? (k ^ 0x80000000u) : ~k);
}
__device__ __forceinline__ short bf16rne(float f) {
    u32 u = __float_as_uint(f);
    u += 0x7FFFu + ((u >> 16) & 1u);
    return (short)(u >> 16);
}

#define GLDS(gp, lp) __builtin_amdgcn_global_load_lds( \
    (const __attribute__((address_space(1))) void*)(gp), \
    (__attribute__((address_space(3))) void*)(lp), 16, 0, 0)

// ---------------------------------------------------------------------------
// prep: codebook -> bf16 (same layout) AND e2[n] = ||e_n||^2. One wave/row.
// ---------------------------------------------------------------------------
__global__ void vq_prep(const float* __restrict__ cb, short* __restrict__ eh,
                        float* __restrict__ e2) {
    const int row  = (blockIdx.x * 256 + threadIdx.x) >> 6;
    const int lane = threadIdx.x & 63;
    const f32x4 v = *(const f32x4*)(cb + (size_t)row * KD + lane * 4);
    short4v h;
    h[0] = bf16rne(v[0]); h[1] = bf16rne(v[1]);
    h[2] = bf16rne(v[2]); h[3] = bf16rne(v[3]);
    *(short4v*)(eh + (size_t)row * KD + lane * 4) = h;
    float s = v[0]*v[0] + v[1]*v[1] + v[2]*v[2] + v[3]*v[3];
    #pragma unroll
    for (int m = 1; m < 64; m <<= 1) s += __shfl_xor(s, m);
    if (lane == 0) e2[row] = s;
}

// ---------------------------------------------------------------------------
// z [b][k][hw] fp32 -> zh [p][k] bf16 (transpose via LDS)
// ---------------------------------------------------------------------------
__global__ void vq_zh(const float* __restrict__ z, short* __restrict__ zh) {
    __shared__ float ts[64][65];
    const int b   = blockIdx.z;
    const int k0  = blockIdx.y * 64;
    const int hw0 = blockIdx.x * 64;
    const int tid = threadIdx.x;
    const int pl  = tid & 63, kk = tid >> 6;
    #pragma unroll
    for (int i = 0; i < 16; ++i) {
        const int k = kk + 4 * i;
        ts[k][pl] = z[b * BCHW + (k0 + k) * HW + hw0 + pl];
    }
    __syncthreads();
    const int tx = tid & 15, ty = tid >> 4;
    #pragma unroll
    for (int j = 0; j < 4; ++j) {
        const int p = ty + 16 * j;
        short4v v;
        #pragma unroll
        for (int q = 0; q < 4; ++q) v[q] = bf16rne(ts[tx * 4 + q][p]);
        *(short4v*)(zh + (size_t)(b * HW + hw0 + p) * KD + k0 + tx * 4) = v;
    }
}

// ---------------------------------------------------------------------------
// Single-pass fused GEMM + argmin + candidate collection.
// 128 pixels x (NT*128) codes per wg, BK=32 x 8 k-steps (FULL K=256),
// dbuf LDS, 4 waves, 4x4 frags of 16x16x32 bf16 MFMA.
// s(p,n) = e2[n]/2 - <zh_p, eh_n>. Publishes per-pixel min to grunmin
// (u32 fkey atomicMin); collects candidates s <= bound+DELTA.
// ---------------------------------------------------------------------------
__global__ __launch_bounds__(256) void vq_gemm(
    const short* __restrict__ zh, const short* __restrict__ eh,
    const float* __restrict__ e2, u32* __restrict__ grunmin,
    u32* __restrict__ flags, u64* __restrict__ cand,
    u32* __restrict__ ncand)
{
    __shared__ short As[2][4096];   // [buf][128 rows x 32 k], row = 32 shorts
    __shared__ short Bs[2][4096];

    const int tid  = threadIdx.x;
    const int lane = tid & 63;
    const int w    = tid >> 6;
    const int wm   = w >> 1, wn = w & 1;
    const int p0   = blockIdx.y * 128;
    const int nb0  = blockIdx.x * (NT * 128);

    // staging: lane l -> row sr = l>>2, linear slot sc = l&3,
    // source slot = sc ^ ((sr>>1)&3)  (inverse of the read swizzle)
    const int sr = lane >> 2;
    const int ss = (lane & 3) ^ ((sr >> 1) & 3);
    // read-side swizzle
    const int q    = lane >> 4;                       // k-quarter (8 shorts)
    const int rsw  = ((lane & 15) >> 1) & 3;          // ((row%16)>>1)&3

    float wbd[4][4];
    int   wbn[4][4];
    #pragma unroll
    for (int m = 0; m < 4; ++m)
        #pragma unroll
        for (int r = 0; r < 4; ++r) { wbd[m][r] = FLT_MAX; wbn[m][r] = 0; }

    #define STAGE(nt_, t_, buf_) do {                                          \
        const int k0_ = (t_) * 32;                                             \
        const int n0_ = nb0 + (nt_) * 128;                                     \
        _Pragma("unroll")                                                      \
        for (int i_ = 0; i_ < 2; ++i_) {                                       \
            const int rb_ = w * 32 + i_ * 16;                                  \
            GLDS(zh + (size_t)(p0 + rb_ + sr) * KD + k0_ + ss * 8,             \
                 &As[buf_][rb_ * 32]);                                         \
            GLDS(eh + (size_t)(n0_ + rb_ + sr) * KD + k0_ + ss * 8,            \
                 &Bs[buf_][rb_ * 32]);                                         \
        }                                                                      \
    } while (0)

    f32x4 acc[4][4];
    float e2h[4];

    STAGE(0, 0, 0);
    __syncthreads();   // vmcnt(0) drain before s_barrier

    #pragma unroll 1
    for (int nt = 0; nt < NT; ++nt) {
        const int n0 = nb0 + nt * 128;
        #pragma unroll
        for (int m = 0; m < 4; ++m)
            #pragma unroll
            for (int nf = 0; nf < 4; ++nf)
                acc[m][nf] = (f32x4){0.f, 0.f, 0.f, 0.f};
        #pragma unroll
        for (int nf = 0; nf < 4; ++nf)
            e2h[nf] = 0.5f * e2[n0 + wn * 64 + nf * 16 + (lane & 15)];

        #pragma unroll
        for (int t = 0; t < 8; ++t) {                 // FULL K: 8 x BK=32
            const int buf = t & 1;
            if (t < 7)            { STAGE(nt, t + 1, buf ^ 1); }
            else if (nt + 1 < NT) { STAGE(nt + 1, 0, buf ^ 1); }

            short8 af[4], bfv[4];
            #pragma unroll
            for (int m = 0; m < 4; ++m) {
                const int row = wm * 64 + m * 16 + (lane & 15);
                af[m] = *(const short8*)&As[buf][row * 32 + ((q ^ rsw) * 8)];
            }
            #pragma unroll
            for (int nf = 0; nf < 4; ++nf) {
                const int row = wn * 64 + nf * 16 + (lane & 15);
                bfv[nf] = *(const short8*)&Bs[buf][row * 32 + ((q ^ rsw) * 8)];
            }
            #pragma unroll
            for (int m = 0; m < 4; ++m)
                #pragma unroll
                for (int nf = 0; nf < 4; ++nf)
                    acc[m][nf] = __builtin_amdgcn_mfma_f32_16x16x32_bf16(
                        af[m], bfv[nf], acc[m][nf], 0, 0, 0);

            if (t == 7) {
                // ---- per-tile epilogue (regs+atomics; before the barrier) --
                const int g = lane >> 4;
                #pragma unroll
                for (int m = 0; m < 4; ++m) {
                    #pragma unroll
                    for (int r = 0; r < 4; ++r) {
                        const int prow = p0 + wm * 64 + m * 16 + g * 4 + r;
                        float dv[4];
                        #pragma unroll
                        for (int nf = 0; nf < 4; ++nf)
                            dv[nf] = e2h[nf] - acc[m][nf][r];
                        // fold nf (ascending n => strict < keeps first)
                        float d = dv[0];
                        int   n = n0 + wn * 64 + (lane & 15);
                        #pragma unroll
                        for (int nf = 1; nf < 4; ++nf) {
                            const int nn = n0 + wn * 64 + nf * 16 + (lane & 15);
                            if (dv[nf] < d) { d = dv[nf]; n = nn; }
                        }
                        // fold across the 16 lanes sharing this pixel
                        #pragma unroll
                        for (int msk = 1; msk < 16; msk <<= 1) {
                            const float od = __shfl_xor(d, msk);
                            const int   on = __shfl_xor(n, msk);
                            if (od < d || (od == d && on < n)) { d = od; n = on; }
                        }
                        if (d < wbd[m][r] || (d == wbd[m][r] && n < wbn[m][r])) {
                            wbd[m][r] = d; wbn[m][r] = n;
                        }
                        if ((lane & 15) == 0) atomicMin(&grunmin[prow], fkey(d));
                        const u32 gk = grunmin[prow];   // fresh-ish, >= final min
                        const float bound = fminf(wbd[m][r], unfkey(gk)) + DELTA;
                        #pragma unroll
                        for (int nf = 0; nf < 4; ++nf) {
                            if (dv[nf] <= bound) {
                                const u32 pos = atomicAdd(ncand, 1u);
                                const int nn = n0 + wn * 64 + nf * 16 + (lane & 15);
                                if (pos < CAND_CAP)
                                    cand[pos] = ((u64)fkey(dv[nf]) << 32) |
                                                ((u32)prow << 13) | (u32)nn;
                                else
                                    flags[prow] = 0u;   // overflow marker
                            }
                        }
                    }
                }
            }
            __syncthreads();
        }
    }
    #undef STAGE
}

// ---------------------------------------------------------------------------
// exact fp32 rescore of candidates (filtered by converged grunmin+DELTA),
// plus full-scan fallback for overflow-flagged pixels.
// ---------------------------------------------------------------------------
__global__ void vq_rescore(const float* __restrict__ z, const float* __restrict__ cb,
                           const float* __restrict__ e2,
                           const u32* __restrict__ grunmin,
                           const u32* __restrict__ flags,
                           const u64* __restrict__ cand,
                           const u32* __restrict__ ncand,
                           u64* __restrict__ final_)
{
    const int gw   = (blockIdx.x * 256 + threadIdx.x) >> 6;
    const int lane = threadIdx.x & 63;
    const int nw   = gridDim.x * 4;
    const u32 nc   = min(*ncand, CAND_CAP);
    for (u32 c = gw; c < nc; c += nw) {
        const u64 e = cand[c];
        const int p = (int)((e >> 13) & 16383u);
        const int n = (int)(e & 8191u);
        const float thr = unfkey(grunmin[p]) + DELTA;
        if (unfkey((u32)(e >> 32)) > thr) continue;
        const int bb = p >> 10, hw = p & 1023;
        const float* zp = z + bb * BCHW + hw;
        const f32x4 ev = *(const f32x4*)(cb + (size_t)n * KD + lane * 4);
        float part = zp[(lane*4+0)*HW]*ev[0] + zp[(lane*4+1)*HW]*ev[1]
                   + zp[(lane*4+2)*HW]*ev[2] + zp[(lane*4+3)*HW]*ev[3];
        #pragma unroll
        for (int m = 1; m < 64; m <<= 1) part += __shfl_xor(part, m);
        if (lane == 0) {
            const float s = 0.5f * e2[n] - part;
            atomicMin(&final_[p], ((u64)fkey(s) << 32) | (u32)n);
        }
    }
    // overflow fallback: exact scan of all codes for flagged pixels
    for (int p = gw; p < NPIX; p += nw) {
        if (flags[p] != 0u) continue;
        const int bb = p >> 10, hw = p & 1023;
        const float* zp = z + bb * BCHW + hw;
        float bd = FLT_MAX; int bn = 0;
        for (int n = lane; n < NE; n += 64) {
            float s = 0.f;
            for (int k = 0; k < KD; ++k) s += zp[k * HW] * cb[(size_t)n * KD + k];
            s = 0.5f * e2[n] - s;
            if (s < bd) { bd = s; bn = n; }
        }
        #pragma unroll
        for (int msk = 1; msk < 64; msk <<= 1) {
            const float od = __shfl_xor(bd, msk);
            const int   on = __shfl_xor(bn, msk);
            if (od < bd || (od == bd && on < bn)) { bd = od; bn = on; }
        }
        if (lane == 0) atomicMin(&final_[p], ((u64)fkey(bd) << 32) | (u32)bn);
    }
}

// ---------------------------------------------------------------------------
// z_q gather + idx unpack + loss = 1.25*mean((z_q - z)^2)
// ---------------------------------------------------------------------------
__global__ void vq_out_kernel(const float* __restrict__ z, const float* __restrict__ cb,
                              const u64* __restrict__ final_, float* __restrict__ out,
                              float* __restrict__ idxf, float* __restrict__ loss)
{
    const int e  = (blockIdx.x * 256 + threadIdx.x) * 4;
    const int bb = e >> 18;
    const int c  = (e >> 10) & 255;
    const int hw = e & 1023;
    const int p  = bb * HW + hw;

    const float4 zv = *reinterpret_cast<const float4*>(z + e);
    const float zl[4] = {zv.x, zv.y, zv.z, zv.w};
    float o[4];
    float ls = 0.f;
    #pragma unroll
    for (int i = 0; i < 4; ++i) {
        const int n = (int)((u32)final_[p + i] & 8191u);
        o[i] = cb[(size_t)n * KD + c];
        if (c == 0) idxf[p + i] = (float)n;
        const float dd = o[i] - zl[i];
        ls += dd * dd;
    }
    const float4 ov = {o[0], o[1], o[2], o[3]};
    *reinterpret_cast<float4*>(out + e) = ov;

    #pragma unroll
    for (int m = 1; m < 64; m <<= 1) ls += __shfl_xor(ls, m);
    if ((threadIdx.x & 63) == 0) atomicAdd(loss, ls * (1.25f / 4194304.f));
}

// ---------------------------------------------------------------------------
extern "C" void kernel_launch(void* const* d_in, const int* in_sizes, int n_in,
                              void* d_out, int out_size, void* d_ws, size_t ws_size,
                              hipStream_t stream) {
    const float* z  = (const float*)d_in[0];
    const float* cb = (const float*)d_in[1];
    float* out  = (float*)d_out;
    float* idxf = out + 4194304;
    float* loss = out + 4210688;
    // scratch inside the z_q region of d_out (fully overwritten at the end):
    short* zh   = (short*)out;                 // [0..8MB)   bf16 z [p][k]
    short* eh   = (short*)(out + 2097152);     // [8..12MB)  bf16 codebook
    u64*   cand = (u64*)(out + 3145728);       // [12..16MB) 512K candidate slots

    char* ws = (char*)d_ws;
    u32*   grunmin = (u32*)ws;               // 64 KB  @ 0
    u32*   flags   = (u32*)(ws + 65536);     // 64 KB
    u64*   final_  = (u64*)(ws + 131072);    // 128 KB
    float* e2      = (float*)(ws + 262144);  // 32 KB
    u32*   ncand   = (u32*)(ws + 294912);    // 4 B

    hipMemsetAsync(ws, 0xFF, 262144, stream);       // grunmin+flags+final_
    hipMemsetAsync(ncand, 0, 4, stream);
    hipMemsetAsync(loss, 0, 4, stream);

    vq_prep<<<2048, 256, 0, stream>>>(cb, eh, e2);
    vq_zh<<<dim3(16, 4, 16), 256, 0, stream>>>(z, zh);
    vq_gemm<<<dim3(NE / (NT * 128), NPIX / 128), 256, 0, stream>>>(
        zh, eh, e2, grunmin, flags, cand, ncand);
    vq_rescore<<<256, 256, 0, stream>>>(z, cb, e2, grunmin, flags, cand, ncand, final_);
    vq_out_kernel<<<4096, 256, 0, stream>>>(z, cb, final_, out, idxf, loss);
}

// Round 6
// 539.513 us; speedup vs baseline: 3.0672x; 3.0672x over previous
//
#include <hip/hip_runtime.h>
#include <float.h>

#define NPIX 16384    // B*H*W pixels
#define NE   8192     // codebook entries
#define KD   256      // channels
#define HW   1024
#define BCHW 262144
#define NT   8        // N-tiles (128 codes) per wg -> wg spans 1024 codes
#define CAND_CAP 524288u
#define DELTA 2.5e-4f // emission/filter window: bf16 err + 2x key quant + e2 spread
#define KMASK 0xFFFFE000u

typedef __attribute__((ext_vector_type(8))) short short8;
typedef __attribute__((ext_vector_type(4))) short short4v;
typedef __attribute__((ext_vector_type(4))) float f32x4;
typedef unsigned long long u64;
typedef unsigned int u32;

__device__ __forceinline__ u32 fkey(float f) {
    u32 u = __float_as_uint(f);
    return u ^ ((u >> 31) ? 0xFFFFFFFFu : 0x80000000u);
}
__device__ __forceinline__ short bf16rne(float f) {
    u32 u = __float_as_uint(f);
    u += 0x7FFFu + ((u >> 16) & 1u);
    return (short)(u >> 16);
}
__device__ __forceinline__ float kval(u32 pk) {   // packed key -> quantized value
    return __uint_as_float(pk & KMASK);
}

#define GLDS(gp, lp) __builtin_amdgcn_global_load_lds( \
    (const __attribute__((address_space(1))) void*)(gp), \
    (__attribute__((address_space(3))) void*)(lp), 16, 0, 0)

// ---------------------------------------------------------------------------
// prep: codebook -> bf16 AND e2[n] = ||e_n||^2. One wave per row.
// ---------------------------------------------------------------------------
__global__ void vq_prep(const float* __restrict__ cb, short* __restrict__ eh,
                        float* __restrict__ e2) {
    const int row  = (blockIdx.x * 256 + threadIdx.x) >> 6;
    const int lane = threadIdx.x & 63;
    const f32x4 v = *(const f32x4*)(cb + (size_t)row * KD + lane * 4);
    short4v h;
    h[0] = bf16rne(v[0]); h[1] = bf16rne(v[1]);
    h[2] = bf16rne(v[2]); h[3] = bf16rne(v[3]);
    *(short4v*)(eh + (size_t)row * KD + lane * 4) = h;
    float s = v[0]*v[0] + v[1]*v[1] + v[2]*v[2] + v[3]*v[3];
    #pragma unroll
    for (int m = 1; m < 64; m <<= 1) s += __shfl_xor(s, m);
    if (lane == 0) e2[row] = s;
}

// ---------------------------------------------------------------------------
// z [b][k][hw] fp32 -> zh [p][k] bf16 (transpose via LDS)
// ---------------------------------------------------------------------------
__global__ void vq_zh(const float* __restrict__ z, short* __restrict__ zh) {
    __shared__ float ts[64][65];
    const int b   = blockIdx.z;
    const int k0  = blockIdx.y * 64;
    const int hw0 = blockIdx.x * 64;
    const int tid = threadIdx.x;
    const int pl  = tid & 63, kk = tid >> 6;
    #pragma unroll
    for (int i = 0; i < 16; ++i) {
        const int k = kk + 4 * i;
        ts[k][pl] = z[b * BCHW + (k0 + k) * HW + hw0 + pl];
    }
    __syncthreads();
    const int tx = tid & 15, ty = tid >> 4;
    #pragma unroll
    for (int j = 0; j < 4; ++j) {
        const int p = ty + 16 * j;
        short4v v;
        #pragma unroll
        for (int q = 0; q < 4; ++q) v[q] = bf16rne(ts[tx * 4 + q][p]);
        *(short4v*)(zh + (size_t)(b * HW + hw0 + p) * KD + k0 + tx * 4) = v;
    }
}

// ---------------------------------------------------------------------------
// Single-pass fused GEMM + argmin + candidate collection.
// 128 pixels x 1024 codes per wg, BK=32 x 8 (full K=256), dbuf LDS,
// 4 waves, 4x4 frags of 16x16x32 bf16 MFMA.
// Per-tile: register-only best-2 per pixel-slot on packed u32 keys
//   pk = (bits(0.0625 - dot) & ~0x1FFF) | n   (positive float -> u32-ordered)
// wg-end: fold bound, emit per-lane b1/b2 within bound+DELTA, one
// ncand atomic per wave, distributed grunmin atomicMin.
// ---------------------------------------------------------------------------
__global__ __launch_bounds__(256) void vq_gemm(
    const short* __restrict__ zh, const short* __restrict__ eh,
    u32* __restrict__ grunmin, u32* __restrict__ flags,
    u64* __restrict__ cand, u32* __restrict__ ncand)
{
    __shared__ short As[2][4096];   // [buf][128 rows x 32 k]
    __shared__ short Bs[2][4096];

    const int tid  = threadIdx.x;
    const int lane = tid & 63;
    const int w    = tid >> 6;
    const int wm   = w >> 1, wn = w & 1;
    const int p0   = blockIdx.y * 128;
    const int nb0  = blockIdx.x * (NT * 128);

    const int sr = lane >> 2;
    const int ss = (lane & 3) ^ ((sr >> 1) & 3);
    const int q   = lane >> 4;
    const int rsw = ((lane & 15) >> 1) & 3;

    u32 b1[4][4], b2[4][4];
    #pragma unroll
    for (int m = 0; m < 4; ++m)
        #pragma unroll
        for (int r = 0; r < 4; ++r) { b1[m][r] = 0xFFFFFFFFu; b2[m][r] = 0xFFFFFFFFu; }

    #define STAGE(nt_, t_, buf_) do {                                          \
        const int k0_ = (t_) * 32;                                             \
        const int n0_ = nb0 + (nt_) * 128;                                     \
        _Pragma("unroll")                                                      \
        for (int i_ = 0; i_ < 2; ++i_) {                                       \
            const int rb_ = w * 32 + i_ * 16;                                  \
            GLDS(zh + (size_t)(p0 + rb_ + sr) * KD + k0_ + ss * 8,             \
                 &As[buf_][rb_ * 32]);                                         \
            GLDS(eh + (size_t)(n0_ + rb_ + sr) * KD + k0_ + ss * 8,            \
                 &Bs[buf_][rb_ * 32]);                                         \
        }                                                                      \
    } while (0)

    f32x4 acc[4][4];

    STAGE(0, 0, 0);
    __syncthreads();

    #pragma unroll 1
    for (int nt = 0; nt < NT; ++nt) {
        #pragma unroll
        for (int m = 0; m < 4; ++m)
            #pragma unroll
            for (int nf = 0; nf < 4; ++nf)
                acc[m][nf] = (f32x4){0.f, 0.f, 0.f, 0.f};

        #pragma unroll
        for (int t = 0; t < 8; ++t) {
            const int buf = t & 1;
            if (t < 7)            { STAGE(nt, t + 1, buf ^ 1); }
            else if (nt + 1 < NT) { STAGE(nt + 1, 0, buf ^ 1); }

            short8 af[4], bfv[4];
            #pragma unroll
            for (int m = 0; m < 4; ++m) {
                const int row = wm * 64 + m * 16 + (lane & 15);
                af[m] = *(const short8*)&As[buf][row * 32 + ((q ^ rsw) * 8)];
            }
            #pragma unroll
            for (int nf = 0; nf < 4; ++nf) {
                const int row = wn * 64 + nf * 16 + (lane & 15);
                bfv[nf] = *(const short8*)&Bs[buf][row * 32 + ((q ^ rsw) * 8)];
            }
            #pragma unroll
            for (int m = 0; m < 4; ++m)
                #pragma unroll
                for (int nf = 0; nf < 4; ++nf)
                    acc[m][nf] = __builtin_amdgcn_mfma_f32_16x16x32_bf16(
                        af[m], bfv[nf], acc[m][nf], 0, 0, 0);

            if (t == 7) {
                // ---- register-only best-2 merge (no shfl, no globals) ----
                const u32 nbase = (u32)(nb0 + nt * 128 + wn * 64 + (lane & 15));
                #pragma unroll
                for (int m = 0; m < 4; ++m) {
                    #pragma unroll
                    for (int r = 0; r < 4; ++r) {
                        u32 pk0 = (__float_as_uint(0.0625f - acc[m][0][r]) & KMASK) | (nbase);
                        u32 pk1 = (__float_as_uint(0.0625f - acc[m][1][r]) & KMASK) | (nbase + 16u);
                        u32 pk2 = (__float_as_uint(0.0625f - acc[m][2][r]) & KMASK) | (nbase + 32u);
                        u32 pk3 = (__float_as_uint(0.0625f - acc[m][3][r]) & KMASK) | (nbase + 48u);
                        const u32 lo01 = min(pk0, pk1), hi01 = max(pk0, pk1);
                        const u32 lo23 = min(pk2, pk3), hi23 = max(pk2, pk3);
                        const u32 m1 = min(lo01, lo23);
                        const u32 m2 = min(max(lo01, lo23), min(hi01, hi23));
                        const u32 nb1 = min(b1[m][r], m1);
                        const u32 nb2 = min(max(b1[m][r], m1), min(b2[m][r], m2));
                        b1[m][r] = nb1; b2[m][r] = nb2;
                    }
                }
            }
            __syncthreads();
        }
    }
    #undef STAGE

    // ---- wg-end: per-pixel bound via 16-lane min-fold of b1 ----
    u32 bmin[4][4];
    #pragma unroll
    for (int m = 0; m < 4; ++m)
        #pragma unroll
        for (int r = 0; r < 4; ++r) {
            u32 v = b1[m][r];
            #pragma unroll
            for (int msk = 1; msk < 16; msk <<= 1)
                v = min(v, (u32)__shfl_xor((int)v, msk));
            bmin[m][r] = v;
        }

    // publish per-pixel slice-min (distributed atomics, 16/wave)
    const int g = lane >> 4;
    if ((lane & 15) == 0) {
        #pragma unroll
        for (int m = 0; m < 4; ++m)
            #pragma unroll
            for (int r = 0; r < 4; ++r)
                atomicMin(&grunmin[p0 + wm * 64 + m * 16 + g * 4 + r], bmin[m][r]);
    }

    // count emissions (every lane: own b1/b2 within bound+DELTA)
    u32 c = 0;
    #pragma unroll
    for (int m = 0; m < 4; ++m)
        #pragma unroll
        for (int r = 0; r < 4; ++r) {
            const float thr = kval(bmin[m][r]) + DELTA;
            c += (kval(b1[m][r]) <= thr) ? 1u : 0u;
            c += (kval(b2[m][r]) <= thr) ? 1u : 0u;
        }

    // wave prefix scan + single ncand atomic per wave
    u32 pre = c;
    #pragma unroll
    for (int d = 1; d < 64; d <<= 1) {
        const u32 t = (u32)__shfl_up((int)pre, d);
        if (lane >= d) pre += t;
    }
    const u32 total = (u32)__shfl((int)pre, 63);
    u32 base = 0;
    if (lane == 63) base = atomicAdd(ncand, total);
    base = (u32)__shfl((int)base, 63);
    u32 off = base + pre - c;

    #pragma unroll
    for (int m = 0; m < 4; ++m)
        #pragma unroll
        for (int r = 0; r < 4; ++r) {
            const int prow = p0 + wm * 64 + m * 16 + g * 4 + r;
            const float thr = kval(bmin[m][r]) + DELTA;
            if (kval(b1[m][r]) <= thr) {
                if (off < CAND_CAP) cand[off] = ((u64)(u32)prow << 32) | b1[m][r];
                else flags[prow] = 0u;
                ++off;
            }
            if (kval(b2[m][r]) <= thr) {
                if (off < CAND_CAP) cand[off] = ((u64)(u32)prow << 32) | b2[m][r];
                else flags[prow] = 0u;
                ++off;
            }
        }
}

// ---------------------------------------------------------------------------
// exact fp32 rescore of candidates filtered by converged grunmin+DELTA,
// plus full-scan fallback for overflow-flagged pixels.
// ---------------------------------------------------------------------------
__global__ void vq_rescore(const float* __restrict__ z, const float* __restrict__ cb,
                           const float* __restrict__ e2,
                           const u32* __restrict__ grunmin,
                           const u32* __restrict__ flags,
                           const u64* __restrict__ cand,
                           const u32* __restrict__ ncand,
                           u64* __restrict__ final_)
{
    const int gw   = (blockIdx.x * 256 + threadIdx.x) >> 6;
    const int lane = threadIdx.x & 63;
    const int nw   = gridDim.x * 4;
    const u32 nc   = min(*ncand, CAND_CAP);
    for (u32 ci = gw; ci < nc; ci += nw) {
        const u64 e = cand[ci];
        const int p = (int)(e >> 32);
        const u32 pk = (u32)e;
        const int n = (int)(pk & 8191u);
        if (kval(pk) > kval(grunmin[p]) + DELTA) continue;
        const int bb = p >> 10, hw = p & 1023;
        const float* zp = z + bb * BCHW + hw;
        const f32x4 ev = *(const f32x4*)(cb + (size_t)n * KD + lane * 4);
        float part = zp[(lane*4+0)*HW]*ev[0] + zp[(lane*4+1)*HW]*ev[1]
                   + zp[(lane*4+2)*HW]*ev[2] + zp[(lane*4+3)*HW]*ev[3];
        #pragma unroll
        for (int m = 1; m < 64; m <<= 1) part += __shfl_xor(part, m);
        if (lane == 0) {
            const float s = 0.5f * e2[n] - part;
            atomicMin(&final_[p], ((u64)fkey(s) << 32) | (u32)n);
        }
    }
    // overflow fallback: exact scan of all codes for flagged pixels
    for (int p = gw; p < NPIX; p += nw) {
        if (flags[p] != 0u) continue;
        const int bb = p >> 10, hw = p & 1023;
        const float* zp = z + bb * BCHW + hw;
        float bd = FLT_MAX; int bn = 0;
        for (int n = lane; n < NE; n += 64) {
            float s = 0.f;
            for (int k = 0; k < KD; ++k) s += zp[k * HW] * cb[(size_t)n * KD + k];
            s = 0.5f * e2[n] - s;
            if (s < bd) { bd = s; bn = n; }
        }
        #pragma unroll
        for (int msk = 1; msk < 64; msk <<= 1) {
            const float od = __shfl_xor(bd, msk);
            const int   on = __shfl_xor(bn, msk);
            if (od < bd || (od == bd && on < bn)) { bd = od; bn = on; }
        }
        if (lane == 0) atomicMin(&final_[p], ((u64)fkey(bd) << 32) | (u32)bn);
    }
}

// ---------------------------------------------------------------------------
// z_q gather + idx unpack + loss = 1.25*mean((z_q - z)^2)
// ---------------------------------------------------------------------------
__global__ void vq_out_kernel(const float* __restrict__ z, const float* __restrict__ cb,
                              const u64* __restrict__ final_, float* __restrict__ out,
                              float* __restrict__ idxf, float* __restrict__ loss)
{
    const int e  = (blockIdx.x * 256 + threadIdx.x) * 4;
    const int bb = e >> 18;
    const int c  = (e >> 10) & 255;
    const int hw = e & 1023;
    const int p  = bb * HW + hw;

    const float4 zv = *reinterpret_cast<const float4*>(z + e);
    const float zl[4] = {zv.x, zv.y, zv.z, zv.w};
    float o[4];
    float ls = 0.f;
    #pragma unroll
    for (int i = 0; i < 4; ++i) {
        const int n = (int)((u32)final_[p + i] & 8191u);
        o[i] = cb[(size_t)n * KD + c];
        if (c == 0) idxf[p + i] = (float)n;
        const float dd = o[i] - zl[i];
        ls += dd * dd;
    }
    const float4 ov = {o[0], o[1], o[2], o[3]};
    *reinterpret_cast<float4*>(out + e) = ov;

    #pragma unroll
    for (int m = 1; m < 64; m <<= 1) ls += __shfl_xor(ls, m);
    if ((threadIdx.x & 63) == 0) atomicAdd(loss, ls * (1.25f / 4194304.f));
}

// ---------------------------------------------------------------------------
extern "C" void kernel_launch(void* const* d_in, const int* in_sizes, int n_in,
                              void* d_out, int out_size, void* d_ws, size_t ws_size,
                              hipStream_t stream) {
    const float* z  = (const float*)d_in[0];
    const float* cb = (const float*)d_in[1];
    float* out  = (float*)d_out;
    float* idxf = out + 4194304;
    float* loss = out + 4210688;
    // scratch inside the z_q region of d_out (fully overwritten at the end):
    short* zh   = (short*)out;                 // [0..8MB)   bf16 z [p][k]
    short* eh   = (short*)(out + 2097152);     // [8..12MB)  bf16 codebook
    u64*   cand = (u64*)(out + 3145728);       // [12..16MB) 512K candidate slots

    char* ws = (char*)d_ws;
    u32*   grunmin = (u32*)ws;               // 64 KB  @ 0
    u32*   flags   = (u32*)(ws + 65536);     // 64 KB
    u64*   final_  = (u64*)(ws + 131072);    // 128 KB
    float* e2      = (float*)(ws + 262144);  // 32 KB
    u32*   ncand   = (u32*)(ws + 294912);    // 4 B

    hipMemsetAsync(ws, 0xFF, 262144, stream);       // grunmin+flags+final_
    hipMemsetAsync(ncand, 0, 4, stream);
    hipMemsetAsync(loss, 0, 4, stream);

    vq_prep<<<2048, 256, 0, stream>>>(cb, eh, e2);
    vq_zh<<<dim3(16, 4, 16), 256, 0, stream>>>(z, zh);
    vq_gemm<<<dim3(NE / (NT * 128), NPIX / 128), 256, 0, stream>>>(
        zh, eh, grunmin, flags, cand, ncand);
    vq_rescore<<<512, 256, 0, stream>>>(z, cb, e2, grunmin, flags, cand, ncand, final_);
    vq_out_kernel<<<4096, 256, 0, stream>>>(z, cb, final_, out, idxf, loss);
}

// Round 7
// 354.815 us; speedup vs baseline: 4.6638x; 1.5205x over previous
//
#include <hip/hip_runtime.h>
#include <float.h>

#define NPIX 16384    // B*H*W pixels
#define NE   8192     // codebook entries
#define KD   256      // channels
#define HW   1024
#define BCHW 262144
#define NT   8        // N-tiles (128 codes) per wg -> wg spans 1024 codes
#define CAND_CAP 524288u
#define DELTA 2.5e-4f // emission/filter window: bf16 err + 2x key quant + e2 spread
#define KMASK 0xFFFFE000u

typedef __attribute__((ext_vector_type(8))) short short8;
typedef __attribute__((ext_vector_type(4))) short short4v;
typedef __attribute__((ext_vector_type(4))) float f32x4;
typedef unsigned long long u64;
typedef unsigned int u32;

__device__ __forceinline__ u32 fkey(float f) {
    u32 u = __float_as_uint(f);
    return u ^ ((u >> 31) ? 0xFFFFFFFFu : 0x80000000u);
}
__device__ __forceinline__ short bf16rne(float f) {
    u32 u = __float_as_uint(f);
    u += 0x7FFFu + ((u >> 16) & 1u);
    return (short)(u >> 16);
}
__device__ __forceinline__ float kval(u32 pk) {   // packed key -> quantized value
    return __uint_as_float(pk & KMASK);
}

#define GLDS(gp, lp) __builtin_amdgcn_global_load_lds( \
    (const __attribute__((address_space(1))) void*)(gp), \
    (__attribute__((address_space(3))) void*)(lp), 16, 0, 0)

// ---------------------------------------------------------------------------
// prep: codebook -> bf16 AND e2[n] = ||e_n||^2. One wave per row.
// ---------------------------------------------------------------------------
__global__ void vq_prep(const float* __restrict__ cb, short* __restrict__ eh,
                        float* __restrict__ e2) {
    const int row  = (blockIdx.x * 256 + threadIdx.x) >> 6;
    const int lane = threadIdx.x & 63;
    const f32x4 v = *(const f32x4*)(cb + (size_t)row * KD + lane * 4);
    short4v h;
    h[0] = bf16rne(v[0]); h[1] = bf16rne(v[1]);
    h[2] = bf16rne(v[2]); h[3] = bf16rne(v[3]);
    *(short4v*)(eh + (size_t)row * KD + lane * 4) = h;
    float s = v[0]*v[0] + v[1]*v[1] + v[2]*v[2] + v[3]*v[3];
    #pragma unroll
    for (int m = 1; m < 64; m <<= 1) s += __shfl_xor(s, m);
    if (lane == 0) e2[row] = s;
}

// ---------------------------------------------------------------------------
// z [b][k][hw] fp32 -> zh [p][k] bf16 (transpose via LDS)
// ---------------------------------------------------------------------------
__global__ void vq_zh(const float* __restrict__ z, short* __restrict__ zh) {
    __shared__ float ts[64][65];
    const int b   = blockIdx.z;
    const int k0  = blockIdx.y * 64;
    const int hw0 = blockIdx.x * 64;
    const int tid = threadIdx.x;
    const int pl  = tid & 63, kk = tid >> 6;
    #pragma unroll
    for (int i = 0; i < 16; ++i) {
        const int k = kk + 4 * i;
        ts[k][pl] = z[b * BCHW + (k0 + k) * HW + hw0 + pl];
    }
    __syncthreads();
    const int tx = tid & 15, ty = tid >> 4;
    #pragma unroll
    for (int j = 0; j < 4; ++j) {
        const int p = ty + 16 * j;
        short4v v;
        #pragma unroll
        for (int q = 0; q < 4; ++q) v[q] = bf16rne(ts[tx * 4 + q][p]);
        *(short4v*)(zh + (size_t)(b * HW + hw0 + p) * KD + k0 + tx * 4) = v;
    }
}

// ---------------------------------------------------------------------------
// Single-pass fused GEMM + argmin + candidate collection.
// 128 pixels x 1024 codes per wg, BK=32 x 8 (full K=256), dbuf LDS,
// 4 waves, 4x4 frags of 16x16x32 bf16 MFMA.
// Per-tile: register-only best-2 per pixel-slot on packed u32 keys
//   pk = (bits(0.0625 - dot) & ~0x1FFF) | n   (positive float -> u32-ordered)
// wg-end: fold bound, emit per-lane b1/b2 within bound+DELTA, one
// ncand atomic per wave, distributed grunmin atomicMin.
// ---------------------------------------------------------------------------
__global__ __launch_bounds__(256) void vq_gemm(
    const short* __restrict__ zh, const short* __restrict__ eh,
    u32* __restrict__ grunmin, u32* __restrict__ flags,
    u64* __restrict__ cand, u32* __restrict__ ncand)
{
    __shared__ short As[2][4096];   // [buf][128 rows x 32 k]
    __shared__ short Bs[2][4096];

    const int tid  = threadIdx.x;
    const int lane = tid & 63;
    const int w    = tid >> 6;
    const int wm   = w >> 1, wn = w & 1;
    const int p0   = blockIdx.y * 128;
    const int nb0  = blockIdx.x * (NT * 128);

    const int sr = lane >> 2;
    const int ss = (lane & 3) ^ ((sr >> 1) & 3);
    const int q   = lane >> 4;
    const int rsw = ((lane & 15) >> 1) & 3;

    u32 b1[4][4], b2[4][4];
    #pragma unroll
    for (int m = 0; m < 4; ++m)
        #pragma unroll
        for (int r = 0; r < 4; ++r) { b1[m][r] = 0xFFFFFFFFu; b2[m][r] = 0xFFFFFFFFu; }

    #define STAGE(nt_, t_, buf_) do {                                          \
        const int k0_ = (t_) * 32;                                             \
        const int n0_ = nb0 + (nt_) * 128;                                     \
        _Pragma("unroll")                                                      \
        for (int i_ = 0; i_ < 2; ++i_) {                                       \
            const int rb_ = w * 32 + i_ * 16;                                  \
            GLDS(zh + (size_t)(p0 + rb_ + sr) * KD + k0_ + ss * 8,             \
                 &As[buf_][rb_ * 32]);                                         \
            GLDS(eh + (size_t)(n0_ + rb_ + sr) * KD + k0_ + ss * 8,            \
                 &Bs[buf_][rb_ * 32]);                                         \
        }                                                                      \
    } while (0)

    f32x4 acc[4][4];

    STAGE(0, 0, 0);
    __syncthreads();

    #pragma unroll 1
    for (int nt = 0; nt < NT; ++nt) {
        #pragma unroll
        for (int m = 0; m < 4; ++m)
            #pragma unroll
            for (int nf = 0; nf < 4; ++nf)
                acc[m][nf] = (f32x4){0.f, 0.f, 0.f, 0.f};

        #pragma unroll
        for (int t = 0; t < 8; ++t) {
            const int buf = t & 1;
            if (t < 7)            { STAGE(nt, t + 1, buf ^ 1); }
            else if (nt + 1 < NT) { STAGE(nt + 1, 0, buf ^ 1); }

            short8 af[4], bfv[4];
            #pragma unroll
            for (int m = 0; m < 4; ++m) {
                const int row = wm * 64 + m * 16 + (lane & 15);
                af[m] = *(const short8*)&As[buf][row * 32 + ((q ^ rsw) * 8)];
            }
            #pragma unroll
            for (int nf = 0; nf < 4; ++nf) {
                const int row = wn * 64 + nf * 16 + (lane & 15);
                bfv[nf] = *(const short8*)&Bs[buf][row * 32 + ((q ^ rsw) * 8)];
            }
            #pragma unroll
            for (int m = 0; m < 4; ++m)
                #pragma unroll
                for (int nf = 0; nf < 4; ++nf)
                    acc[m][nf] = __builtin_amdgcn_mfma_f32_16x16x32_bf16(
                        af[m], bfv[nf], acc[m][nf], 0, 0, 0);

            if (t == 7) {
                // ---- register-only best-2 merge (no shfl, no globals) ----
                const u32 nbase = (u32)(nb0 + nt * 128 + wn * 64 + (lane & 15));
                #pragma unroll
                for (int m = 0; m < 4; ++m) {
                    #pragma unroll
                    for (int r = 0; r < 4; ++r) {
                        u32 pk0 = (__float_as_uint(0.0625f - acc[m][0][r]) & KMASK) | (nbase);
                        u32 pk1 = (__float_as_uint(0.0625f - acc[m][1][r]) & KMASK) | (nbase + 16u);
                        u32 pk2 = (__float_as_uint(0.0625f - acc[m][2][r]) & KMASK) | (nbase + 32u);
                        u32 pk3 = (__float_as_uint(0.0625f - acc[m][3][r]) & KMASK) | (nbase + 48u);
                        const u32 lo01 = min(pk0, pk1), hi01 = max(pk0, pk1);
                        const u32 lo23 = min(pk2, pk3), hi23 = max(pk2, pk3);
                        const u32 m1 = min(lo01, lo23);
                        const u32 m2 = min(max(lo01, lo23), min(hi01, hi23));
                        const u32 nb1 = min(b1[m][r], m1);
                        const u32 nb2 = min(max(b1[m][r], m1), min(b2[m][r], m2));
                        b1[m][r] = nb1; b2[m][r] = nb2;
                    }
                }
            }
            __syncthreads();
        }
    }
    #undef STAGE

    // ---- wg-end: per-pixel bound via 16-lane min-fold of b1 ----
    u32 bmin[4][4];
    #pragma unroll
    for (int m = 0; m < 4; ++m)
        #pragma unroll
        for (int r = 0; r < 4; ++r) {
            u32 v = b1[m][r];
            #pragma unroll
            for (int msk = 1; msk < 16; msk <<= 1)
                v = min(v, (u32)__shfl_xor((int)v, msk));
            bmin[m][r] = v;
        }

    // publish per-pixel slice-min (distributed atomics, 16/wave)
    const int g = lane >> 4;
    if ((lane & 15) == 0) {
        #pragma unroll
        for (int m = 0; m < 4; ++m)
            #pragma unroll
            for (int r = 0; r < 4; ++r)
                atomicMin(&grunmin[p0 + wm * 64 + m * 16 + g * 4 + r], bmin[m][r]);
    }

    // count emissions (every lane: own b1/b2 within bound+DELTA)
    u32 c = 0;
    #pragma unroll
    for (int m = 0; m < 4; ++m)
        #pragma unroll
        for (int r = 0; r < 4; ++r) {
            const float thr = kval(bmin[m][r]) + DELTA;
            c += (kval(b1[m][r]) <= thr) ? 1u : 0u;
            c += (kval(b2[m][r]) <= thr) ? 1u : 0u;
        }

    // wave prefix scan + single ncand atomic per wave
    u32 pre = c;
    #pragma unroll
    for (int d = 1; d < 64; d <<= 1) {
        const u32 t = (u32)__shfl_up((int)pre, d);
        if (lane >= d) pre += t;
    }
    const u32 total = (u32)__shfl((int)pre, 63);
    u32 base = 0;
    if (lane == 63) base = atomicAdd(ncand, total);
    base = (u32)__shfl((int)base, 63);
    u32 off = base + pre - c;

    #pragma unroll
    for (int m = 0; m < 4; ++m)
        #pragma unroll
        for (int r = 0; r < 4; ++r) {
            const int prow = p0 + wm * 64 + m * 16 + g * 4 + r;
            const float thr = kval(bmin[m][r]) + DELTA;
            if (kval(b1[m][r]) <= thr) {
                if (off < CAND_CAP) cand[off] = ((u64)(u32)prow << 32) | b1[m][r];
                else flags[prow] = 0u;
                ++off;
            }
            if (kval(b2[m][r]) <= thr) {
                if (off < CAND_CAP) cand[off] = ((u64)(u32)prow << 32) | b2[m][r];
                else flags[prow] = 0u;
                ++off;
            }
        }
}

// ---------------------------------------------------------------------------
// exact fp32 rescore of candidates filtered by converged grunmin+DELTA,
// plus full-scan fallback for overflow-flagged pixels.
// ---------------------------------------------------------------------------
__global__ void vq_rescore(const float* __restrict__ z, const float* __restrict__ cb,
                           const float* __restrict__ e2,
                           const u32* __restrict__ grunmin,
                           const u32* __restrict__ flags,
                           const u64* __restrict__ cand,
                           const u32* __restrict__ ncand,
                           u64* __restrict__ final_)
{
    const int gw   = (blockIdx.x * 256 + threadIdx.x) >> 6;
    const int lane = threadIdx.x & 63;
    const int nw   = gridDim.x * 4;
    const u32 nc   = min(*ncand, CAND_CAP);
    for (u32 ci = gw; ci < nc; ci += nw) {
        const u64 e = cand[ci];
        const int p = (int)(e >> 32);
        const u32 pk = (u32)e;
        const int n = (int)(pk & 8191u);
        if (kval(pk) > kval(grunmin[p]) + DELTA) continue;
        const int bb = p >> 10, hw = p & 1023;
        const float* zp = z + bb * BCHW + hw;
        const f32x4 ev = *(const f32x4*)(cb + (size_t)n * KD + lane * 4);
        float part = zp[(lane*4+0)*HW]*ev[0] + zp[(lane*4+1)*HW]*ev[1]
                   + zp[(lane*4+2)*HW]*ev[2] + zp[(lane*4+3)*HW]*ev[3];
        #pragma unroll
        for (int m = 1; m < 64; m <<= 1) part += __shfl_xor(part, m);
        if (lane == 0) {
            const float s = 0.5f * e2[n] - part;
            atomicMin(&final_[p], ((u64)fkey(s) << 32) | (u32)n);
        }
    }
    // overflow fallback: exact scan of all codes for flagged pixels
    for (int p = gw; p < NPIX; p += nw) {
        if (flags[p] != 0u) continue;
        const int bb = p >> 10, hw = p & 1023;
        const float* zp = z + bb * BCHW + hw;
        float bd = FLT_MAX; int bn = 0;
        for (int n = lane; n < NE; n += 64) {
            float s = 0.f;
            for (int k = 0; k < KD; ++k) s += zp[k * HW] * cb[(size_t)n * KD + k];
            s = 0.5f * e2[n] - s;
            if (s < bd) { bd = s; bn = n; }
        }
        #pragma unroll
        for (int msk = 1; msk < 64; msk <<= 1) {
            const float od = __shfl_xor(bd, msk);
            const int   on = __shfl_xor(bn, msk);
            if (od < bd || (od == bd && on < bn)) { bd = od; bn = on; }
        }
        if (lane == 0) atomicMin(&final_[p], ((u64)fkey(bd) << 32) | (u32)bn);
    }
}

// ---------------------------------------------------------------------------
// Output kernel, tile-transposed: 32 pixels x 256 channels per wg.
// Phase 1: read final_ -> indices (+idxf write). Phase 2: gather the 32
// selected codebook ROWS coalesced into LDS. Phase 3: write z_q channel-
// first as float4 across pixels (coalesced) fused with loss accumulation.
// ---------------------------------------------------------------------------
__global__ __launch_bounds__(256) void vq_out_kernel(
    const float* __restrict__ z, const float* __restrict__ cb,
    const u64* __restrict__ final_, float* __restrict__ out,
    float* __restrict__ idxf, float* __restrict__ loss)
{
    __shared__ float zq[32][257];
    __shared__ int   nidx[32];

    const int tid = threadIdx.x;
    const int p0  = blockIdx.x * 32;           // 32 pixels, within one batch
    const int bb  = p0 >> 10;
    const int hw0 = p0 & 1023;

    if (tid < 32) {
        const int n = (int)((u32)final_[p0 + tid] & 8191u);
        nidx[tid] = n;
        idxf[p0 + tid] = (float)n;
    }
    __syncthreads();

    // gather 32 rows x 256 floats: 8 threads per row, f32x4 each, 8 iters
    {
        const int r = tid >> 3, i = tid & 7;
        const float* src = cb + (size_t)nidx[r] * KD;
        #pragma unroll
        for (int j = 0; j < 8; ++j) {
            const int col = i * 4 + j * 32;
            const f32x4 v = *(const f32x4*)(src + col);
            zq[r][col + 0] = v[0]; zq[r][col + 1] = v[1];
            zq[r][col + 2] = v[2]; zq[r][col + 3] = v[3];
        }
    }
    __syncthreads();

    // write channel-first + loss: lane covers pixels p4..p4+3 at channel c
    const int p4 = (tid & 7) * 4;
    const int cg = tid >> 3;                   // 32 channel groups
    float ls = 0.f;
    #pragma unroll
    for (int ii = 0; ii < 8; ++ii) {
        const int c = cg + 32 * ii;
        const size_t e = (size_t)bb * BCHW + (size_t)c * HW + hw0 + p4;
        const f32x4 zv = *(const f32x4*)(z + e);
        f32x4 v;
        v[0] = zq[p4 + 0][c]; v[1] = zq[p4 + 1][c];
        v[2] = zq[p4 + 2][c]; v[3] = zq[p4 + 3][c];
        *(f32x4*)(out + e) = v;
        const float d0 = v[0] - zv[0], d1 = v[1] - zv[1];
        const float d2 = v[2] - zv[2], d3 = v[3] - zv[3];
        ls += d0 * d0 + d1 * d1 + d2 * d2 + d3 * d3;
    }
    #pragma unroll
    for (int m = 1; m < 64; m <<= 1) ls += __shfl_xor(ls, m);
    if ((tid & 63) == 0) atomicAdd(loss, ls * (1.25f / 4194304.f));
}

// ---------------------------------------------------------------------------
extern "C" void kernel_launch(void* const* d_in, const int* in_sizes, int n_in,
                              void* d_out, int out_size, void* d_ws, size_t ws_size,
                              hipStream_t stream) {
    const float* z  = (const float*)d_in[0];
    const float* cb = (const float*)d_in[1];
    float* out  = (float*)d_out;
    float* idxf = out + 4194304;
    float* loss = out + 4210688;
    // scratch inside the z_q region of d_out (fully overwritten at the end):
    short* zh   = (short*)out;                 // [0..8MB)   bf16 z [p][k]
    short* eh   = (short*)(out + 2097152);     // [8..12MB)  bf16 codebook
    u64*   cand = (u64*)(out + 3145728);       // [12..16MB) 512K candidate slots

    char* ws = (char*)d_ws;
    u32*   grunmin = (u32*)ws;               // 64 KB  @ 0
    u32*   flags   = (u32*)(ws + 65536);     // 64 KB
    u64*   final_  = (u64*)(ws + 131072);    // 128 KB
    float* e2      = (float*)(ws + 262144);  // 32 KB
    u32*   ncand   = (u32*)(ws + 294912);    // 4 B

    hipMemsetAsync(ws, 0xFF, 262144, stream);       // grunmin+flags+final_
    hipMemsetAsync(ncand, 0, 4, stream);
    hipMemsetAsync(loss, 0, 4, stream);

    vq_prep<<<2048, 256, 0, stream>>>(cb, eh, e2);
    vq_zh<<<dim3(16, 4, 16), 256, 0, stream>>>(z, zh);
    vq_gemm<<<dim3(NE / (NT * 128), NPIX / 128), 256, 0, stream>>>(
        zh, eh, grunmin, flags, cand, ncand);
    vq_rescore<<<512, 256, 0, stream>>>(z, cb, e2, grunmin, flags, cand, ncand, final_);
    vq_out_kernel<<<NPIX / 32, 256, 0, stream>>>(z, cb, final_, out, idxf, loss);
}